// Round 17
// baseline (329.120 us; speedup 1.0000x reference)
//
#include <hip/hip_runtime.h>
#include <hip/hip_bf16.h>
#include <cstdint>
#include <cstddef>

#define B_    16
#define LQ    30
#define LD    1100
#define DIM   768
#define NH    12
#define DH_   64
#define WINSZ 11
#define WNUM  100
#define NSLOT 32              // 2 docs x 16 batches

typedef __attribute__((ext_vector_type(8))) short short8;
typedef __attribute__((ext_vector_type(4))) float f32x4;

__device__ __forceinline__ void gload_lds16(const void* g, void* l) {
  __builtin_amdgcn_global_load_lds(
      (const __attribute__((address_space(1))) void*)g,
      (__attribute__((address_space(3))) void*)l, 16, 0, 0);
}

// ---------------------------------------------------------------------------
// prologue (merged): wconv (weights fp32->bf16), pe table, prep_q.
// ---------------------------------------------------------------------------
#define WCONV_B ((DIM * DIM / 4 + 255) / 256)        // 576
#define PE_B    ((LD * (DIM / 4) + 255) / 256)       // 825
#define PQ_B    ((B_ * LQ * (DIM / 4) + 255) / 256)  // 360

__global__ __launch_bounds__(256) void prologue_kernel(
    const float* __restrict__ wa, const float* __restrict__ wb,
    __hip_bfloat16* __restrict__ oa, __hip_bfloat16* __restrict__ ob,
    float* __restrict__ pe,
    const int* __restrict__ q, const float* __restrict__ qmask,
    const float* __restrict__ emb, __hip_bfloat16* __restrict__ Xq) {
  int bx = blockIdx.x;
  if (bx < WCONV_B) {
    int i = (bx * 256 + threadIdx.x) * 4;
    if (i >= DIM * DIM) return;
    float4 va = *reinterpret_cast<const float4*>(wa + i);
    float4 vb = *reinterpret_cast<const float4*>(wb + i);
    union { __hip_bfloat16 h[4]; uint2 u; } pa, pb;
    pa.h[0] = __float2bfloat16(va.x); pa.h[1] = __float2bfloat16(va.y);
    pa.h[2] = __float2bfloat16(va.z); pa.h[3] = __float2bfloat16(va.w);
    pb.h[0] = __float2bfloat16(vb.x); pb.h[1] = __float2bfloat16(vb.y);
    pb.h[2] = __float2bfloat16(vb.z); pb.h[3] = __float2bfloat16(vb.w);
    *reinterpret_cast<uint2*>(oa + i) = pa.u;
    *reinterpret_cast<uint2*>(ob + i) = pb.u;
  } else if (bx < WCONV_B + PE_B) {
    int idx = (bx - WCONV_B) * 256 + threadIdx.x;
    if (idx >= LD * (DIM / 4)) return;
    int t  = idx / (DIM / 4);
    int c4 = idx % (DIM / 4);
    int i0 = c4 * 2;
    float d0 = expf(-0.023985261387f * (float)i0);
    float d1 = expf(-0.023985261387f * (float)(i0 + 1));
    float s0f, c0f, s1f, c1f;
    sincosf((float)t * d0, &s0f, &c0f);
    sincosf((float)t * d1, &s1f, &c1f);
    *reinterpret_cast<float4*>(pe + (size_t)t * DIM + c4 * 4) =
        make_float4(s0f, c0f, s1f, c1f);
  } else {
    int idx = (bx - WCONV_B - PE_B) * 256 + threadIdx.x;
    if (idx >= B_ * LQ * (DIM / 4)) return;
    int row = idx / (DIM / 4);
    int c4  = idx % (DIM / 4);
    float m = qmask[row] * 0.125f;
    float4 v = *reinterpret_cast<const float4*>(emb + (size_t)q[row] * DIM + c4 * 4);
    union { __hip_bfloat16 h[4]; uint2 u; } o;
    o.h[0] = __float2bfloat16(v.x * m); o.h[1] = __float2bfloat16(v.y * m);
    o.h[2] = __float2bfloat16(v.z * m); o.h[3] = __float2bfloat16(v.w * m);
    *reinterpret_cast<uint2*>(Xq + (size_t)row * DIM + c4 * 4) = o.u;
  }
}

// ---------------------------------------------------------------------------
// prep_d (both docs), 8-wide (verified R16).
// ---------------------------------------------------------------------------
__global__ __launch_bounds__(256) void prep_d_kernel(const int* __restrict__ dpos,
    const int* __restrict__ dneg, const float* __restrict__ dpmask,
    const float* __restrict__ dnmask, const float* __restrict__ emb,
    const int* __restrict__ peflag, const float* __restrict__ pe,
    __hip_bfloat16* __restrict__ X, int s0, int rows) {
  int idx = blockIdx.x * 256 + threadIdx.x;        // rows * 96 octs
  if (idx >= rows * (DIM / 8)) return;
  int r  = idx / (DIM / 8);
  int c8 = idx % (DIM / 8);
  int col = c8 * 8;
  int s = s0 + r / LD;
  int t = r % LD;
  int doc = s >> 4, b = s & 15;
  const int*   di = doc ? dneg   : dpos;
  const float* dm = doc ? dnmask : dpmask;
  int grow = b * LD + t;
  float m = dm[grow];
  const float* ep = emb + (size_t)di[grow] * DIM + col;
  float4 v0 = *reinterpret_cast<const float4*>(ep);
  float4 v1 = *reinterpret_cast<const float4*>(ep + 4);
  if (peflag[0]) {
    const float* pp = pe + (size_t)t * DIM + col;
    float4 p0 = *reinterpret_cast<const float4*>(pp);
    float4 p1 = *reinterpret_cast<const float4*>(pp + 4);
    v0.x = v0.x * 27.712812921102035f + p0.x;
    v0.y = v0.y * 27.712812921102035f + p0.y;
    v0.z = v0.z * 27.712812921102035f + p0.z;
    v0.w = v0.w * 27.712812921102035f + p0.w;
    v1.x = v1.x * 27.712812921102035f + p1.x;
    v1.y = v1.y * 27.712812921102035f + p1.y;
    v1.z = v1.z * 27.712812921102035f + p1.z;
    v1.w = v1.w * 27.712812921102035f + p1.w;
  }
  union { __hip_bfloat16 h[8]; uint4 u; } o;
  o.h[0] = __float2bfloat16(v0.x * m); o.h[1] = __float2bfloat16(v0.y * m);
  o.h[2] = __float2bfloat16(v0.z * m); o.h[3] = __float2bfloat16(v0.w * m);
  o.h[4] = __float2bfloat16(v1.x * m); o.h[5] = __float2bfloat16(v1.y * m);
  o.h[6] = __float2bfloat16(v1.z * m); o.h[7] = __float2bfloat16(v1.w * m);
  *reinterpret_cast<uint4*>(X + (size_t)r * DIM + col) = o.u;
}

// ---------------------------------------------------------------------------
// gemm_mfma: R15/R16 kernel with ONE change: mid-tile hardware barriers
// (P1/P2/P3 entries) dropped — replaced by sched_barrier(0) only.
// Correctness: all WAR pairs (stage during tile t vs reads during tile t-1)
// and RAW pairs (per-wave vmcnt(4) + block barrier) are separated by each
// tile's P0 s_barrier, which is kept. Waves free-run within a tile, spreading
// the CU-shared LDS read traffic instead of convoying at every phase.
// ---------------------------------------------------------------------------
template <bool OUT_BF16>
__global__ __launch_bounds__(512, 2) void gemm_mfma(const __hip_bfloat16* __restrict__ A,
    const __hip_bfloat16* __restrict__ Bt, void* __restrict__ Cv,
    int M, int N, int K, int tilesX, int tiles1,
    const __hip_bfloat16* __restrict__ A2, float* __restrict__ C2, int M2) {
  extern __shared__ __hip_bfloat16 smem[];
  // A: slot0 [0,16384), slot1 [16384,32768); B: 32768 + slot*16384.

  const int nwg  = gridDim.x;
  const int orig = blockIdx.x;
  const int q8 = nwg >> 3, r8 = nwg & 7;
  const int xcd = orig & 7, pos = orig >> 3;
  const int wgid = (xcd < r8 ? xcd * (q8 + 1) : r8 * (q8 + 1) + (xcd - r8) * q8) + pos;

  const bool is2 = (wgid >= tiles1);
  const int  w2  = is2 ? (wgid - tiles1) : wgid;
  const int row0 = (w2 / tilesX) * 256;
  const int col0 = (w2 % tilesX) * 256;
  const __hip_bfloat16* Ap = is2 ? A2 : A;
  const int Mloc = is2 ? M2 : M;

  const int tid  = threadIdx.x;
  const int lane = tid & 63;
  const int wave = tid >> 6;
  const int wr = wave >> 2, wc = wave & 3;     // 2 x 4 waves
  const int lo4 = lane & 15;
  const int hi4 = lane >> 4;

  const int u0 = tid,        r0s = u0 >> 3, x0s = u0 & 7;
  const int u1 = 512 + tid,  r1s = u1 >> 3, x1s = u1 & 7;
  const int soff0 = r0s * K + ((x0s ^ (r0s & 7)) * 8);
  const int soff1 = r1s * K + ((x1s ^ (r1s & 7)) * 8);
  const int wvoff = wave * 512;                // dest elems (wave-uniform)
  const __hip_bfloat16* gA = Ap + (size_t)row0 * K;
  const __hip_bfloat16* gB = Bt + (size_t)col0 * K;

#define STAGE_HALF(PTR, KOFF, HALF, SLOTBASE)                            \
  gload_lds16((PTR) + (size_t)(HALF) * (128 * 768) + (KOFF) + soff0,    \
              smem + (SLOTBASE) + (HALF) * 8192 + wvoff);               \
  gload_lds16((PTR) + (size_t)(HALF) * (128 * 768) + (KOFF) + soff1,    \
              smem + (SLOTBASE) + (HALF) * 8192 + 4096 + wvoff);

  const int rA = (wr * 128 + lo4) * 64;        // + m*1024
  const int rB = (wc * 64  + lo4) * 64;        // + n*1024
  const int xk0 = ((0 + hi4) ^ (lo4 & 7)) * 8; // kk = 0
  const int xk1 = ((4 + hi4) ^ (lo4 & 7)) * 8; // kk = 1

#define LDA(S, MM, XK) (*reinterpret_cast<const short8*>(smem + (S) * 16384 + rA + (MM) * 1024 + (XK)))
#define LDB(S, NN, XK) (*reinterpret_cast<const short8*>(smem + 32768 + (S) * 16384 + rB + (NN) * 1024 + (XK)))

  f32x4 acc[8][4] = {};
  short8 bf[4][2];
  short8 xa0, xa1, xa2, xa3;   // ping set
  short8 ya0, ya1, ya2, ya3;   // pong set

#define MM4R(MMI, KK, AREG)                                                        \
  acc[MMI][0] = __builtin_amdgcn_mfma_f32_16x16x32_bf16(bf[0][KK], AREG, acc[MMI][0], 0, 0, 0); \
  acc[MMI][1] = __builtin_amdgcn_mfma_f32_16x16x32_bf16(bf[1][KK], AREG, acc[MMI][1], 0, 0, 0); \
  acc[MMI][2] = __builtin_amdgcn_mfma_f32_16x16x32_bf16(bf[2][KK], AREG, acc[MMI][2], 0, 0, 0); \
  acc[MMI][3] = __builtin_amdgcn_mfma_f32_16x16x32_bf16(bf[3][KK], AREG, acc[MMI][3], 0, 0, 0);
#define MFMA4R(MA, MB, R0, R1, R2, R3) \
  MM4R(MA, 0, R0) MM4R(MB, 0, R1) MM4R(MA, 1, R2) MM4R(MB, 1, R3)

#define LDB8(S)                                                          \
  bf[0][0] = LDB(S, 0, xk0); bf[1][0] = LDB(S, 1, xk0);                  \
  bf[2][0] = LDB(S, 2, xk0); bf[3][0] = LDB(S, 3, xk0);                  \
  bf[0][1] = LDB(S, 0, xk1); bf[1][1] = LDB(S, 1, xk1);                  \
  bf[2][1] = LDB(S, 2, xk1); bf[3][1] = LDB(S, 3, xk1);
#define LDA4R(S, MA, MB, R0, R1, R2, R3)                                 \
  R0 = LDA(S, MA, xk0); R1 = LDA(S, MB, xk0);                            \
  R2 = LDA(S, MA, xk1); R3 = LDA(S, MB, xk1);

#define BARR  { __builtin_amdgcn_s_barrier(); __builtin_amdgcn_sched_barrier(0); }
#define BARRX { __builtin_amdgcn_sched_barrier(0); }     // phase edge, no hw sync
#define VMW(NLIT) asm volatile("s_waitcnt vmcnt(" NLIT ")" ::: "memory");
#define PH_SYNC(NLIT) { asm volatile("s_waitcnt lgkmcnt(" NLIT ")" ::: "memory"); \
                        __builtin_amdgcn_sched_barrier(0);               \
                        __builtin_amdgcn_s_setprio(1); }
#define PH_END  __builtin_amdgcn_s_setprio(0);

  // ---- prologue: stage B(0), A(0), B(1) ----
  STAGE_HALF(gB, 0,   0, 32768) STAGE_HALF(gB, 0,   1, 32768)
  STAGE_HALF(gA, 0,   0, 0)     STAGE_HALF(gA, 0,   1, 0)
  STAGE_HALF(gB, 64,  0, 49152) STAGE_HALF(gB, 64,  1, 49152)

  for (int it = 0; it < 5; ++it) {
    const int kb = it * 128;
    // ---- group 0 (slot0, tile 2it) ----
    VMW("4") BARR
    LDB8(0)
    LDA4R(0, 0, 1, xa0, xa1, xa2, xa3)
    LDA4R(0, 2, 3, ya0, ya1, ya2, ya3)          // pre-read P1
    STAGE_HALF(gA, kb + 64, 0, 16384)
    PH_SYNC("4") MFMA4R(0, 1, xa0, xa1, xa2, xa3) PH_END
    BARRX
    LDA4R(0, 4, 5, xa0, xa1, xa2, xa3)          // pre-read P2
    STAGE_HALF(gA, kb + 64, 1, 16384)
    PH_SYNC("4") MFMA4R(2, 3, ya0, ya1, ya2, ya3) PH_END
    BARRX
    LDA4R(0, 6, 7, ya0, ya1, ya2, ya3)          // pre-read P3
    STAGE_HALF(gB, kb + 128, 0, 32768)
    PH_SYNC("4") MFMA4R(4, 5, xa0, xa1, xa2, xa3) PH_END
    BARRX
    STAGE_HALF(gB, kb + 128, 1, 32768)
    PH_SYNC("0") MFMA4R(6, 7, ya0, ya1, ya2, ya3) PH_END
    // ---- group 1 (slot1, tile 2it+1) ----
    VMW("4") BARR
    LDB8(1)
    LDA4R(1, 0, 1, xa0, xa1, xa2, xa3)
    LDA4R(1, 2, 3, ya0, ya1, ya2, ya3)
    STAGE_HALF(gA, kb + 128, 0, 0)
    PH_SYNC("4") MFMA4R(0, 1, xa0, xa1, xa2, xa3) PH_END
    BARRX
    LDA4R(1, 4, 5, xa0, xa1, xa2, xa3)
    STAGE_HALF(gA, kb + 128, 1, 0)
    PH_SYNC("4") MFMA4R(2, 3, ya0, ya1, ya2, ya3) PH_END
    BARRX
    LDA4R(1, 6, 7, ya0, ya1, ya2, ya3)
    STAGE_HALF(gB, kb + 192, 0, 49152)
    PH_SYNC("4") MFMA4R(4, 5, xa0, xa1, xa2, xa3) PH_END
    BARRX
    STAGE_HALF(gB, kb + 192, 1, 49152)
    PH_SYNC("0") MFMA4R(6, 7, ya0, ya1, ya2, ya3) PH_END
  }

  // ---- epilogue group 0 (slot0, tile 10; stages A(11)) ----
  VMW("4") BARR
  LDB8(0)
  LDA4R(0, 0, 1, xa0, xa1, xa2, xa3)
  LDA4R(0, 2, 3, ya0, ya1, ya2, ya3)
  STAGE_HALF(gA, 704, 0, 16384)
  PH_SYNC("4") MFMA4R(0, 1, xa0, xa1, xa2, xa3) PH_END
  BARRX
  LDA4R(0, 4, 5, xa0, xa1, xa2, xa3)
  STAGE_HALF(gA, 704, 1, 16384)
  PH_SYNC("4") MFMA4R(2, 3, ya0, ya1, ya2, ya3) PH_END
  BARRX
  LDA4R(0, 6, 7, ya0, ya1, ya2, ya3)
  PH_SYNC("4") MFMA4R(4, 5, xa0, xa1, xa2, xa3) PH_END
  BARRX
  PH_SYNC("0") MFMA4R(6, 7, ya0, ya1, ya2, ya3) PH_END
  // ---- epilogue group 1 (slot1, tile 11; no stages) ----
  VMW("0") BARR
  LDB8(1)
  LDA4R(1, 0, 1, xa0, xa1, xa2, xa3)
  LDA4R(1, 2, 3, ya0, ya1, ya2, ya3)
  PH_SYNC("4") MFMA4R(0, 1, xa0, xa1, xa2, xa3) PH_END
  BARRX
  LDA4R(1, 4, 5, xa0, xa1, xa2, xa3)
  PH_SYNC("4") MFMA4R(2, 3, ya0, ya1, ya2, ya3) PH_END
  BARRX
  LDA4R(1, 6, 7, ya0, ya1, ya2, ya3)
  PH_SYNC("4") MFMA4R(4, 5, xa0, xa1, xa2, xa3) PH_END
  BARRX
  PH_SYNC("0") MFMA4R(6, 7, ya0, ya1, ya2, ya3) PH_END

#undef STAGE_HALF
#undef LDA
#undef LDB
#undef MM4R
#undef MFMA4R
#undef LDB8
#undef LDA4R
#undef BARR
#undef BARRX
#undef VMW
#undef PH_SYNC
#undef PH_END

  // epilogue (swapped layout): lane holds C[row = ..+lo4][col = ..+hi4*4+j]
#pragma unroll
  for (int m = 0; m < 8; ++m) {
    const int r = row0 + wr * 128 + m * 16 + lo4;
    if (r < Mloc) {
#pragma unroll
      for (int n = 0; n < 4; ++n) {
        const int cb = col0 + wc * 64 + n * 16 + hi4 * 4;
        f32x4 v = acc[m][n];
        if (is2) {
          *reinterpret_cast<f32x4*>(C2 + (size_t)r * N + cb) = v;
        } else if constexpr (OUT_BF16) {
          union { __hip_bfloat16 h[4]; uint2 u; } p;
          p.h[0] = __float2bfloat16(v[0]); p.h[1] = __float2bfloat16(v[1]);
          p.h[2] = __float2bfloat16(v[2]); p.h[3] = __float2bfloat16(v[3]);
          *reinterpret_cast<uint2*>((__hip_bfloat16*)Cv + (size_t)r * N + cb) = p.u;
        } else {
          __builtin_nontemporal_store(
              v, reinterpret_cast<f32x4*>((float*)Cv + (size_t)r * N + cb));
        }
      }
    }
  }
}

// ---------------------------------------------------------------------------
// attn v4 (MFMA): EXACT R16 kernel (verified, absmax 4.88e-3).
// ---------------------------------------------------------------------------
__global__ __launch_bounds__(64) void attn_kernel(const float* __restrict__ Qs,
    const __hip_bfloat16* __restrict__ Y, __hip_bfloat16* __restrict__ ctx, int s0) {
  __shared__ alignas(16) __hip_bfloat16 Dk[16][80];   // [k][dh], rows>=11 stale (masked)
  __shared__ alignas(16) __hip_bfloat16 DlT[64][40];  // [dh][k], cols>=11 stale (P=0)

  const int blk = blockIdx.x;
  const int w  = blk % WNUM;
  const int sl = blk / WNUM;
  const int b  = (s0 + sl) & 15;

  const int lane = threadIdx.x;
  const int lo4 = lane & 15, hi4 = lane >> 4;

  const __hip_bfloat16* Yw = Y + ((size_t)(sl * LD + w * WINSZ)) * DIM;
  const float* Qb = Qs + (size_t)(b * LQ) * DIM;
  __hip_bfloat16* cb = ctx + (size_t)(sl * WNUM + w) * (LQ * DIM);

  for (int h = 0; h < NH; ++h) {
    const uint4* src = reinterpret_cast<const uint4*>(Yw + h * (WINSZ * DH_));
    uint4 r0 = src[lane];
    uint4 r1 = (lane < 24) ? src[64 + lane] : make_uint4(0, 0, 0, 0);
    {
      int k = lane >> 3, d0 = (lane & 7) * 8;
      *reinterpret_cast<uint4*>(&Dk[k][d0]) = r0;
      const __hip_bfloat16* hp = reinterpret_cast<const __hip_bfloat16*>(&r0);
#pragma unroll
      for (int j = 0; j < 8; ++j) DlT[d0 + j][k] = hp[j];
    }
    if (lane < 24) {
      int i = 64 + lane;
      int k = i >> 3, d0 = (i & 7) * 8;
      *reinterpret_cast<uint4*>(&Dk[k][d0]) = r1;
      const __hip_bfloat16* hp = reinterpret_cast<const __hip_bfloat16*>(&r1);
#pragma unroll
      for (int j = 0; j < 8; ++j) DlT[d0 + j][k] = hp[j];
    }
    asm volatile("s_waitcnt lgkmcnt(0)" ::: "memory");

    f32x4 sT[2] = {};
#pragma unroll
    for (int half = 0; half < 2; ++half) {
      short8 dfrag = *reinterpret_cast<const short8*>(&Dk[lo4][half * 32 + hi4 * 8]);
#pragma unroll
      for (int qt = 0; qt < 2; ++qt) {
        const float* qp = Qb + (size_t)(qt * 16 + lo4) * DIM + h * 64 + half * 32 + hi4 * 8;
        float4 qa = *reinterpret_cast<const float4*>(qp);
        float4 qc = *reinterpret_cast<const float4*>(qp + 4);
        union { __hip_bfloat16 hh[8]; short8 s; } qf;
        qf.hh[0] = __float2bfloat16(qa.x); qf.hh[1] = __float2bfloat16(qa.y);
        qf.hh[2] = __float2bfloat16(qa.z); qf.hh[3] = __float2bfloat16(qa.w);
        qf.hh[4] = __float2bfloat16(qc.x); qf.hh[5] = __float2bfloat16(qc.y);
        qf.hh[6] = __float2bfloat16(qc.z); qf.hh[7] = __float2bfloat16(qc.w);
        sT[qt] = __builtin_amdgcn_mfma_f32_16x16x32_bf16(dfrag, qf.s, sT[qt], 0, 0, 0);
      }
    }

    uint pk[2][2];
#pragma unroll
    for (int qt = 0; qt < 2; ++qt) {
      float mx = -1e30f;
#pragma unroll
      for (int j = 0; j < 4; ++j) {
        int k = hi4 * 4 + j;
        if (k < WINSZ) mx = fmaxf(mx, sT[qt][j]);
      }
      mx = fmaxf(mx, __shfl_xor(mx, 16));
      mx = fmaxf(mx, __shfl_xor(mx, 32));
      float p[4]; float sum = 0.f;
#pragma unroll
      for (int j = 0; j < 4; ++j) {
        int k = hi4 * 4 + j;
        p[j] = (k < WINSZ) ? expf(sT[qt][j] - mx) : 0.f;
        sum += p[j];
      }
      sum += __shfl_xor(sum, 16);
      sum += __shfl_xor(sum, 32);
      float iv = 1.f / sum;
      union { __hip_bfloat16 h[2]; uint u; } u01, u23;
      u01.h[0] = __float2bfloat16(p[0] * iv); u01.h[1] = __float2bfloat16(p[1] * iv);
      u23.h[0] = __float2bfloat16(p[2] * iv); u23.h[1] = __float2bfloat16(p[3] * iv);
      pk[qt][0] = u01.u; pk[qt][1] = u23.u;
    }

    short8 pfrag[2];
    {
      int g0 = ((hi4 * 2) & 3) * 16 + lo4;
      int g1 = ((hi4 * 2 + 1) & 3) * 16 + lo4;
#pragma unroll
      for (int qt = 0; qt < 2; ++qt) {
        uint w0 = __builtin_amdgcn_ds_bpermute(g0 * 4, pk[qt][0]);
        uint w1 = __builtin_amdgcn_ds_bpermute(g0 * 4, pk[qt][1]);
        uint w2 = __builtin_amdgcn_ds_bpermute(g1 * 4, pk[qt][0]);
        uint w3 = __builtin_amdgcn_ds_bpermute(g1 * 4, pk[qt][1]);
        if (hi4 >= 2) { w0 = 0; w1 = 0; w2 = 0; w3 = 0; }
        union { uint u[4]; short8 s; } asm8;
        asm8.u[0] = w0; asm8.u[1] = w1; asm8.u[2] = w2; asm8.u[3] = w3;
        pfrag[qt] = asm8.s;
      }
    }

    f32x4 oacc[4][2] = {};
    __builtin_amdgcn_s_setprio(1);
#pragma unroll
    for (int dt = 0; dt < 4; ++dt) {
      short8 dtf = *reinterpret_cast<const short8*>(&DlT[dt * 16 + lo4][hi4 * 8]);
#pragma unroll
      for (int qt = 0; qt < 2; ++qt)
        oacc[dt][qt] = __builtin_amdgcn_mfma_f32_16x16x32_bf16(dtf, pfrag[qt], oacc[dt][qt], 0, 0, 0);
    }
    __builtin_amdgcn_s_setprio(0);

#pragma unroll
    for (int qt = 0; qt < 2; ++qt) {
      int q = qt * 16 + lo4;
      if (q < LQ) {
#pragma unroll
        for (int dt = 0; dt < 4; ++dt) {
          f32x4 v = oacc[dt][qt];
          union { __hip_bfloat16 h[4]; uint2 u; } p;
          p.h[0] = __float2bfloat16(v[0]); p.h[1] = __float2bfloat16(v[1]);
          p.h[2] = __float2bfloat16(v[2]); p.h[3] = __float2bfloat16(v[3]);
          *reinterpret_cast<uint2*>(cb + h * (LQ * DH_) + q * DH_ + dt * 16 + hi4 * 4) = p.u;
        }
      }
    }
    asm volatile("s_waitcnt lgkmcnt(0)" ::: "memory");
  }
}

// ---------------------------------------------------------------------------
extern "C" void kernel_launch(void* const* d_in, const int* in_sizes, int n_in,
                              void* d_out, int out_size, void* d_ws, size_t ws_size,
                              hipStream_t stream) {
  const int*   q      = (const int*)d_in[0];
  const int*   dpos   = (const int*)d_in[1];
  const int*   dneg   = (const int*)d_in[2];
  const float* qmask  = (const float*)d_in[3];
  const float* dpmask = (const float*)d_in[4];
  const float* dnmask = (const float*)d_in[5];
  const int*   peflag = (const int*)d_in[6];
  const float* emb    = (const float*)d_in[7];
  const float* Wlin   = (const float*)d_in[8];
  const float* Wout   = (const float*)d_in[9];
  float* out = (float*)d_out;

  (void)hipFuncSetAttribute(reinterpret_cast<const void*>(&gemm_mfma<false>),
                            hipFuncAttributeMaxDynamicSharedMemorySize, 131072);
  (void)hipFuncSetAttribute(reinterpret_cast<const void*>(&gemm_mfma<true>),
                            hipFuncAttributeMaxDynamicSharedMemorySize, 131072);

  char* ws = (char*)d_ws;
  size_t off = 0;
  auto alloc = [&](size_t bytes) -> char* {
    char* p = ws + off; off += (bytes + 255) & ~(size_t)255; return p;
  };
  __hip_bfloat16* Xq   = (__hip_bfloat16*)alloc((size_t)512 * DIM * 2);  // 480 rows + tile pad
  float*          Qsc  = (float*)         alloc((size_t)512 * DIM * 4);  // 480 rows + pad (attn over-reads q=30,31)
  __hip_bfloat16* Wl16 = (__hip_bfloat16*)alloc((size_t)DIM * DIM * 2);
  __hip_bfloat16* Wo16 = (__hip_bfloat16*)alloc((size_t)DIM * DIM * 2);
  float*          PE   = (float*)         alloc((size_t)LD * DIM * 4);   // 3.4 MB

  int SC = NSLOT;
  while (SC > 1) {
    size_t need = off
        + ((size_t)SC * LD + 256) * DIM * 2 * 2                 // X + Y
        + ((size_t)SC * WNUM * LQ + 256) * DIM * 2 + (1u << 20);// ctx
    if (need <= ws_size) break;
    SC >>= 1;
  }
  __hip_bfloat16* X   = (__hip_bfloat16*)alloc(((size_t)SC * LD + 256) * DIM * 2);
  __hip_bfloat16* Y   = (__hip_bfloat16*)alloc(((size_t)SC * LD + 256) * DIM * 2);
  __hip_bfloat16* ctx = (__hip_bfloat16*)alloc(((size_t)SC * WNUM * LQ + 256) * DIM * 2);

  prologue_kernel<<<WCONV_B + PE_B + PQ_B, 256, 0, stream>>>(
      Wlin, Wout, Wl16, Wo16, PE, q, qmask, emb, Xq);

  const int tilesX = DIM / 256;                       // 3
  const int qTiles = tilesX * ((B_ * LQ + 255) / 256);// 6 (Q-problem blocks)

  for (int s0 = 0; s0 < NSLOT; s0 += SC) {
    const int rowsX = SC * LD;           // 35200 at SC=32
    const int rowsC = SC * WNUM * LQ;    // 96000 at SC=32
    prep_d_kernel<<<(rowsX * (DIM / 8) + 255) / 256, 256, 0, stream>>>(
        dpos, dneg, dpmask, dnmask, emb, peflag, PE, X, s0, rowsX);
    {
      int tiles1 = tilesX * ((rowsX + 255) / 256);
      int t2 = (s0 == 0) ? qTiles : 0;
      gemm_mfma<true><<<tiles1 + t2, 512, 131072, stream>>>(
          X, Wl16, Y, rowsX, DIM, DIM, tilesX, tiles1, Xq, Qsc, B_ * LQ);
    }
    attn_kernel<<<SC * WNUM, 64, 0, stream>>>(Qsc, Y, ctx, s0);
    {
      int tiles1 = tilesX * ((rowsC + 255) / 256);
      gemm_mfma<false><<<tiles1, 512, 131072, stream>>>(
          ctx, Wo16, out + (size_t)s0 * WNUM * LQ * DIM, rowsC, DIM, DIM,
          tilesX, tiles1, nullptr, nullptr, 0);
    }
  }
}

// Round 19
// 327.692 us; speedup vs baseline: 1.0044x; 1.0044x over previous
//
#include <hip/hip_runtime.h>
#include <hip/hip_bf16.h>
#include <cstdint>
#include <cstddef>

#define B_    16
#define LQ    30
#define LD    1100
#define DIM   768
#define NH    12
#define DH_   64
#define WINSZ 11
#define WNUM  100
#define NSLOT 32              // 2 docs x 16 batches

typedef __attribute__((ext_vector_type(8))) short short8;
typedef __attribute__((ext_vector_type(4))) float f32x4;

__device__ __forceinline__ void gload_lds16(const void* g, void* l) {
  __builtin_amdgcn_global_load_lds(
      (const __attribute__((address_space(1))) void*)g,
      (__attribute__((address_space(3))) void*)l, 16, 0, 0);
}

// ---------------------------------------------------------------------------
// prologue (merged): wconv (weights fp32->bf16), pe table, prep_q.
// ---------------------------------------------------------------------------
#define WCONV_B ((DIM * DIM / 4 + 255) / 256)        // 576
#define PE_B    ((LD * (DIM / 4) + 255) / 256)       // 825
#define PQ_B    ((B_ * LQ * (DIM / 4) + 255) / 256)  // 360

__global__ __launch_bounds__(256) void prologue_kernel(
    const float* __restrict__ wa, const float* __restrict__ wb,
    __hip_bfloat16* __restrict__ oa, __hip_bfloat16* __restrict__ ob,
    float* __restrict__ pe,
    const int* __restrict__ q, const float* __restrict__ qmask,
    const float* __restrict__ emb, __hip_bfloat16* __restrict__ Xq) {
  int bx = blockIdx.x;
  if (bx < WCONV_B) {
    int i = (bx * 256 + threadIdx.x) * 4;
    if (i >= DIM * DIM) return;
    float4 va = *reinterpret_cast<const float4*>(wa + i);
    float4 vb = *reinterpret_cast<const float4*>(wb + i);
    union { __hip_bfloat16 h[4]; uint2 u; } pa, pb;
    pa.h[0] = __float2bfloat16(va.x); pa.h[1] = __float2bfloat16(va.y);
    pa.h[2] = __float2bfloat16(va.z); pa.h[3] = __float2bfloat16(va.w);
    pb.h[0] = __float2bfloat16(vb.x); pb.h[1] = __float2bfloat16(vb.y);
    pb.h[2] = __float2bfloat16(vb.z); pb.h[3] = __float2bfloat16(vb.w);
    *reinterpret_cast<uint2*>(oa + i) = pa.u;
    *reinterpret_cast<uint2*>(ob + i) = pb.u;
  } else if (bx < WCONV_B + PE_B) {
    int idx = (bx - WCONV_B) * 256 + threadIdx.x;
    if (idx >= LD * (DIM / 4)) return;
    int t  = idx / (DIM / 4);
    int c4 = idx % (DIM / 4);
    int i0 = c4 * 2;
    float d0 = expf(-0.023985261387f * (float)i0);
    float d1 = expf(-0.023985261387f * (float)(i0 + 1));
    float s0f, c0f, s1f, c1f;
    sincosf((float)t * d0, &s0f, &c0f);
    sincosf((float)t * d1, &s1f, &c1f);
    *reinterpret_cast<float4*>(pe + (size_t)t * DIM + c4 * 4) =
        make_float4(s0f, c0f, s1f, c1f);
  } else {
    int idx = (bx - WCONV_B - PE_B) * 256 + threadIdx.x;
    if (idx >= B_ * LQ * (DIM / 4)) return;
    int row = idx / (DIM / 4);
    int c4  = idx % (DIM / 4);
    float m = qmask[row] * 0.125f;
    float4 v = *reinterpret_cast<const float4*>(emb + (size_t)q[row] * DIM + c4 * 4);
    union { __hip_bfloat16 h[4]; uint2 u; } o;
    o.h[0] = __float2bfloat16(v.x * m); o.h[1] = __float2bfloat16(v.y * m);
    o.h[2] = __float2bfloat16(v.z * m); o.h[3] = __float2bfloat16(v.w * m);
    *reinterpret_cast<uint2*>(Xq + (size_t)row * DIM + c4 * 4) = o.u;
  }
}

// ---------------------------------------------------------------------------
// prep_d (both docs), 8-wide (verified R16).
// ---------------------------------------------------------------------------
__global__ __launch_bounds__(256) void prep_d_kernel(const int* __restrict__ dpos,
    const int* __restrict__ dneg, const float* __restrict__ dpmask,
    const float* __restrict__ dnmask, const float* __restrict__ emb,
    const int* __restrict__ peflag, const float* __restrict__ pe,
    __hip_bfloat16* __restrict__ X, int s0, int rows) {
  int idx = blockIdx.x * 256 + threadIdx.x;        // rows * 96 octs
  if (idx >= rows * (DIM / 8)) return;
  int r  = idx / (DIM / 8);
  int c8 = idx % (DIM / 8);
  int col = c8 * 8;
  int s = s0 + r / LD;
  int t = r % LD;
  int doc = s >> 4, b = s & 15;
  const int*   di = doc ? dneg   : dpos;
  const float* dm = doc ? dnmask : dpmask;
  int grow = b * LD + t;
  float m = dm[grow];
  const float* ep = emb + (size_t)di[grow] * DIM + col;
  float4 v0 = *reinterpret_cast<const float4*>(ep);
  float4 v1 = *reinterpret_cast<const float4*>(ep + 4);
  if (peflag[0]) {
    const float* pp = pe + (size_t)t * DIM + col;
    float4 p0 = *reinterpret_cast<const float4*>(pp);
    float4 p1 = *reinterpret_cast<const float4*>(pp + 4);
    v0.x = v0.x * 27.712812921102035f + p0.x;
    v0.y = v0.y * 27.712812921102035f + p0.y;
    v0.z = v0.z * 27.712812921102035f + p0.z;
    v0.w = v0.w * 27.712812921102035f + p0.w;
    v1.x = v1.x * 27.712812921102035f + p1.x;
    v1.y = v1.y * 27.712812921102035f + p1.y;
    v1.z = v1.z * 27.712812921102035f + p1.z;
    v1.w = v1.w * 27.712812921102035f + p1.w;
  }
  union { __hip_bfloat16 h[8]; uint4 u; } o;
  o.h[0] = __float2bfloat16(v0.x * m); o.h[1] = __float2bfloat16(v0.y * m);
  o.h[2] = __float2bfloat16(v0.z * m); o.h[3] = __float2bfloat16(v0.w * m);
  o.h[4] = __float2bfloat16(v1.x * m); o.h[5] = __float2bfloat16(v1.y * m);
  o.h[6] = __float2bfloat16(v1.z * m); o.h[7] = __float2bfloat16(v1.w * m);
  *reinterpret_cast<uint4*>(X + (size_t)r * DIM + col) = o.u;
}

// ---------------------------------------------------------------------------
// gemm_mfma: R15/R16 kernel (verified 327.9 us) — 8-phase, counted vmcnt,
// one-phase-ahead ds_read pipelining, chunk-XOR swizzle both-sides,
// swapped-operand vectorized epilogue, dual-problem Q-fusion, NT out store.
// ---------------------------------------------------------------------------
template <bool OUT_BF16>
__global__ __launch_bounds__(512, 2) void gemm_mfma(const __hip_bfloat16* __restrict__ A,
    const __hip_bfloat16* __restrict__ Bt, void* __restrict__ Cv,
    int M, int N, int K, int tilesX, int tiles1,
    const __hip_bfloat16* __restrict__ A2, float* __restrict__ C2, int M2) {
  extern __shared__ __hip_bfloat16 smem[];
  // A: slot0 [0,16384), slot1 [16384,32768); B: 32768 + slot*16384.

  const int nwg  = gridDim.x;
  const int orig = blockIdx.x;
  const int q8 = nwg >> 3, r8 = nwg & 7;
  const int xcd = orig & 7, pos = orig >> 3;
  const int wgid = (xcd < r8 ? xcd * (q8 + 1) : r8 * (q8 + 1) + (xcd - r8) * q8) + pos;

  const bool is2 = (wgid >= tiles1);
  const int  w2  = is2 ? (wgid - tiles1) : wgid;
  const int row0 = (w2 / tilesX) * 256;
  const int col0 = (w2 % tilesX) * 256;
  const __hip_bfloat16* Ap = is2 ? A2 : A;
  const int Mloc = is2 ? M2 : M;

  const int tid  = threadIdx.x;
  const int lane = tid & 63;
  const int wave = tid >> 6;
  const int wr = wave >> 2, wc = wave & 3;     // 2 x 4 waves
  const int lo4 = lane & 15;
  const int hi4 = lane >> 4;

  const int u0 = tid,        r0s = u0 >> 3, x0s = u0 & 7;
  const int u1 = 512 + tid,  r1s = u1 >> 3, x1s = u1 & 7;
  const int soff0 = r0s * K + ((x0s ^ (r0s & 7)) * 8);
  const int soff1 = r1s * K + ((x1s ^ (r1s & 7)) * 8);
  const int wvoff = wave * 512;                // dest elems (wave-uniform)
  const __hip_bfloat16* gA = Ap + (size_t)row0 * K;
  const __hip_bfloat16* gB = Bt + (size_t)col0 * K;

#define STAGE_HALF(PTR, KOFF, HALF, SLOTBASE)                            \
  gload_lds16((PTR) + (size_t)(HALF) * (128 * 768) + (KOFF) + soff0,    \
              smem + (SLOTBASE) + (HALF) * 8192 + wvoff);               \
  gload_lds16((PTR) + (size_t)(HALF) * (128 * 768) + (KOFF) + soff1,    \
              smem + (SLOTBASE) + (HALF) * 8192 + 4096 + wvoff);

  const int rA = (wr * 128 + lo4) * 64;        // + m*1024
  const int rB = (wc * 64  + lo4) * 64;        // + n*1024
  const int xk0 = ((0 + hi4) ^ (lo4 & 7)) * 8; // kk = 0
  const int xk1 = ((4 + hi4) ^ (lo4 & 7)) * 8; // kk = 1

#define LDA(S, MM, XK) (*reinterpret_cast<const short8*>(smem + (S) * 16384 + rA + (MM) * 1024 + (XK)))
#define LDB(S, NN, XK) (*reinterpret_cast<const short8*>(smem + 32768 + (S) * 16384 + rB + (NN) * 1024 + (XK)))

  f32x4 acc[8][4] = {};
  short8 bf[4][2];
  short8 xa0, xa1, xa2, xa3;   // ping set
  short8 ya0, ya1, ya2, ya3;   // pong set

#define MM4R(MMI, KK, AREG)                                                        \
  acc[MMI][0] = __builtin_amdgcn_mfma_f32_16x16x32_bf16(bf[0][KK], AREG, acc[MMI][0], 0, 0, 0); \
  acc[MMI][1] = __builtin_amdgcn_mfma_f32_16x16x32_bf16(bf[1][KK], AREG, acc[MMI][1], 0, 0, 0); \
  acc[MMI][2] = __builtin_amdgcn_mfma_f32_16x16x32_bf16(bf[2][KK], AREG, acc[MMI][2], 0, 0, 0); \
  acc[MMI][3] = __builtin_amdgcn_mfma_f32_16x16x32_bf16(bf[3][KK], AREG, acc[MMI][3], 0, 0, 0);
#define MFMA4R(MA, MB, R0, R1, R2, R3) \
  MM4R(MA, 0, R0) MM4R(MB, 0, R1) MM4R(MA, 1, R2) MM4R(MB, 1, R3)

#define LDB8(S)                                                          \
  bf[0][0] = LDB(S, 0, xk0); bf[1][0] = LDB(S, 1, xk0);                  \
  bf[2][0] = LDB(S, 2, xk0); bf[3][0] = LDB(S, 3, xk0);                  \
  bf[0][1] = LDB(S, 0, xk1); bf[1][1] = LDB(S, 1, xk1);                  \
  bf[2][1] = LDB(S, 2, xk1); bf[3][1] = LDB(S, 3, xk1);
#define LDA4R(S, MA, MB, R0, R1, R2, R3)                                 \
  R0 = LDA(S, MA, xk0); R1 = LDA(S, MB, xk0);                            \
  R2 = LDA(S, MA, xk1); R3 = LDA(S, MB, xk1);

#define BARR  { __builtin_amdgcn_s_barrier(); __builtin_amdgcn_sched_barrier(0); }
#define VMW(NLIT) asm volatile("s_waitcnt vmcnt(" NLIT ")" ::: "memory");
#define PH_SYNC(NLIT) { asm volatile("s_waitcnt lgkmcnt(" NLIT ")" ::: "memory"); \
                        __builtin_amdgcn_sched_barrier(0);               \
                        __builtin_amdgcn_s_setprio(1); }
#define PH_END  __builtin_amdgcn_s_setprio(0);

  // ---- prologue: stage B(0), A(0), B(1) ----
  STAGE_HALF(gB, 0,   0, 32768) STAGE_HALF(gB, 0,   1, 32768)
  STAGE_HALF(gA, 0,   0, 0)     STAGE_HALF(gA, 0,   1, 0)
  STAGE_HALF(gB, 64,  0, 49152) STAGE_HALF(gB, 64,  1, 49152)

  for (int it = 0; it < 5; ++it) {
    const int kb = it * 128;
    // ---- group 0 (slot0, tile 2it) ----
    VMW("4") BARR
    LDB8(0)
    LDA4R(0, 0, 1, xa0, xa1, xa2, xa3)
    LDA4R(0, 2, 3, ya0, ya1, ya2, ya3)          // pre-read P1
    STAGE_HALF(gA, kb + 64, 0, 16384)
    PH_SYNC("4") MFMA4R(0, 1, xa0, xa1, xa2, xa3) PH_END
    BARR
    LDA4R(0, 4, 5, xa0, xa1, xa2, xa3)          // pre-read P2
    STAGE_HALF(gA, kb + 64, 1, 16384)
    PH_SYNC("4") MFMA4R(2, 3, ya0, ya1, ya2, ya3) PH_END
    BARR
    LDA4R(0, 6, 7, ya0, ya1, ya2, ya3)          // pre-read P3
    STAGE_HALF(gB, kb + 128, 0, 32768)
    PH_SYNC("4") MFMA4R(4, 5, xa0, xa1, xa2, xa3) PH_END
    BARR
    STAGE_HALF(gB, kb + 128, 1, 32768)
    PH_SYNC("0") MFMA4R(6, 7, ya0, ya1, ya2, ya3) PH_END
    // ---- group 1 (slot1, tile 2it+1) ----
    VMW("4") BARR
    LDB8(1)
    LDA4R(1, 0, 1, xa0, xa1, xa2, xa3)
    LDA4R(1, 2, 3, ya0, ya1, ya2, ya3)
    STAGE_HALF(gA, kb + 128, 0, 0)
    PH_SYNC("4") MFMA4R(0, 1, xa0, xa1, xa2, xa3) PH_END
    BARR
    LDA4R(1, 4, 5, xa0, xa1, xa2, xa3)
    STAGE_HALF(gA, kb + 128, 1, 0)
    PH_SYNC("4") MFMA4R(2, 3, ya0, ya1, ya2, ya3) PH_END
    BARR
    LDA4R(1, 6, 7, ya0, ya1, ya2, ya3)
    STAGE_HALF(gB, kb + 192, 0, 49152)
    PH_SYNC("4") MFMA4R(4, 5, xa0, xa1, xa2, xa3) PH_END
    BARR
    STAGE_HALF(gB, kb + 192, 1, 49152)
    PH_SYNC("0") MFMA4R(6, 7, ya0, ya1, ya2, ya3) PH_END
  }

  // ---- epilogue group 0 (slot0, tile 10; stages A(11)) ----
  VMW("4") BARR
  LDB8(0)
  LDA4R(0, 0, 1, xa0, xa1, xa2, xa3)
  LDA4R(0, 2, 3, ya0, ya1, ya2, ya3)
  STAGE_HALF(gA, 704, 0, 16384)
  PH_SYNC("4") MFMA4R(0, 1, xa0, xa1, xa2, xa3) PH_END
  BARR
  LDA4R(0, 4, 5, xa0, xa1, xa2, xa3)
  STAGE_HALF(gA, 704, 1, 16384)
  PH_SYNC("4") MFMA4R(2, 3, ya0, ya1, ya2, ya3) PH_END
  BARR
  LDA4R(0, 6, 7, ya0, ya1, ya2, ya3)
  PH_SYNC("4") MFMA4R(4, 5, xa0, xa1, xa2, xa3) PH_END
  BARR
  PH_SYNC("0") MFMA4R(6, 7, ya0, ya1, ya2, ya3) PH_END
  // ---- epilogue group 1 (slot1, tile 11; no stages) ----
  VMW("0") BARR
  LDB8(1)
  LDA4R(1, 0, 1, xa0, xa1, xa2, xa3)
  LDA4R(1, 2, 3, ya0, ya1, ya2, ya3)
  PH_SYNC("4") MFMA4R(0, 1, xa0, xa1, xa2, xa3) PH_END
  BARR
  LDA4R(1, 4, 5, xa0, xa1, xa2, xa3)
  PH_SYNC("4") MFMA4R(2, 3, ya0, ya1, ya2, ya3) PH_END
  BARR
  LDA4R(1, 6, 7, ya0, ya1, ya2, ya3)
  PH_SYNC("4") MFMA4R(4, 5, xa0, xa1, xa2, xa3) PH_END
  BARR
  PH_SYNC("0") MFMA4R(6, 7, ya0, ya1, ya2, ya3) PH_END

#undef STAGE_HALF
#undef LDA
#undef LDB
#undef MM4R
#undef MFMA4R
#undef LDB8
#undef LDA4R
#undef BARR
#undef VMW
#undef PH_SYNC
#undef PH_END

  // epilogue (swapped layout): lane holds C[row = ..+lo4][col = ..+hi4*4+j]
#pragma unroll
  for (int m = 0; m < 8; ++m) {
    const int r = row0 + wr * 128 + m * 16 + lo4;
    if (r < Mloc) {
#pragma unroll
      for (int n = 0; n < 4; ++n) {
        const int cb = col0 + wc * 64 + n * 16 + hi4 * 4;
        f32x4 v = acc[m][n];
        if (is2) {
          *reinterpret_cast<f32x4*>(C2 + (size_t)r * N + cb) = v;
        } else if constexpr (OUT_BF16) {
          union { __hip_bfloat16 h[4]; uint2 u; } p;
          p.h[0] = __float2bfloat16(v[0]); p.h[1] = __float2bfloat16(v[1]);
          p.h[2] = __float2bfloat16(v[2]); p.h[3] = __float2bfloat16(v[3]);
          *reinterpret_cast<uint2*>((__hip_bfloat16*)Cv + (size_t)r * N + cb) = p.u;
        } else {
          __builtin_nontemporal_store(
              v, reinterpret_cast<f32x4*>((float*)Cv + (size_t)r * N + cb));
        }
      }
    }
  }
}

// ---------------------------------------------------------------------------
// attn v4 (MFMA): R14 kernel + s_setprio around the PV MFMA cluster (T5).
// ---------------------------------------------------------------------------
__global__ __launch_bounds__(64) void attn_kernel(const float* __restrict__ Qs,
    const __hip_bfloat16* __restrict__ Y, __hip_bfloat16* __restrict__ ctx, int s0) {
  __shared__ alignas(16) __hip_bfloat16 Dk[16][80];   // [k][dh], rows>=11 stale (masked)
  __shared__ alignas(16) __hip_bfloat16 DlT[64][40];  // [dh][k], cols>=11 stale (P=0)

  const int blk = blockIdx.x;
  const int w  = blk % WNUM;
  const int sl = blk / WNUM;
  const int b  = (s0 + sl) & 15;

  const int lane = threadIdx.x;
  const int lo4 = lane & 15, hi4 = lane >> 4;

  const __hip_bfloat16* Yw = Y + ((size_t)(sl * LD + w * WINSZ)) * DIM;
  const float* Qb = Qs + (size_t)(b * LQ) * DIM;
  __hip_bfloat16* cb = ctx + (size_t)(sl * WNUM + w) * (LQ * DIM);

  for (int h = 0; h < NH; ++h) {
    const uint4* src = reinterpret_cast<const uint4*>(Yw + h * (WINSZ * DH_));
    uint4 r0 = src[lane];
    uint4 r1 = (lane < 24) ? src[64 + lane] : make_uint4(0, 0, 0, 0);
    {
      int k = lane >> 3, d0 = (lane & 7) * 8;
      *reinterpret_cast<uint4*>(&Dk[k][d0]) = r0;
      const __hip_bfloat16* hp = reinterpret_cast<const __hip_bfloat16*>(&r0);
#pragma unroll
      for (int j = 0; j < 8; ++j) DlT[d0 + j][k] = hp[j];
    }
    if (lane < 24) {
      int i = 64 + lane;
      int k = i >> 3, d0 = (i & 7) * 8;
      *reinterpret_cast<uint4*>(&Dk[k][d0]) = r1;
      const __hip_bfloat16* hp = reinterpret_cast<const __hip_bfloat16*>(&r1);
#pragma unroll
      for (int j = 0; j < 8; ++j) DlT[d0 + j][k] = hp[j];
    }
    asm volatile("s_waitcnt lgkmcnt(0)" ::: "memory");

    f32x4 sT[2] = {};
#pragma unroll
    for (int half = 0; half < 2; ++half) {
      short8 dfrag = *reinterpret_cast<const short8*>(&Dk[lo4][half * 32 + hi4 * 8]);
#pragma unroll
      for (int qt = 0; qt < 2; ++qt) {
        const float* qp = Qb + (size_t)(qt * 16 + lo4) * DIM + h * 64 + half * 32 + hi4 * 8;
        float4 qa = *reinterpret_cast<const float4*>(qp);
        float4 qc = *reinterpret_cast<const float4*>(qp + 4);
        union { __hip_bfloat16 hh[8]; short8 s; } qf;
        qf.hh[0] = __float2bfloat16(qa.x); qf.hh[1] = __float2bfloat16(qa.y);
        qf.hh[2] = __float2bfloat16(qa.z); qf.hh[3] = __float2bfloat16(qa.w);
        qf.hh[4] = __float2bfloat16(qc.x); qf.hh[5] = __float2bfloat16(qc.y);
        qf.hh[6] = __float2bfloat16(qc.z); qf.hh[7] = __float2bfloat16(qc.w);
        sT[qt] = __builtin_amdgcn_mfma_f32_16x16x32_bf16(dfrag, qf.s, sT[qt], 0, 0, 0);
      }
    }

    uint pk[2][2];
#pragma unroll
    for (int qt = 0; qt < 2; ++qt) {
      float mx = -1e30f;
#pragma unroll
      for (int j = 0; j < 4; ++j) {
        int k = hi4 * 4 + j;
        if (k < WINSZ) mx = fmaxf(mx, sT[qt][j]);
      }
      mx = fmaxf(mx, __shfl_xor(mx, 16));
      mx = fmaxf(mx, __shfl_xor(mx, 32));
      float p[4]; float sum = 0.f;
#pragma unroll
      for (int j = 0; j < 4; ++j) {
        int k = hi4 * 4 + j;
        p[j] = (k < WINSZ) ? expf(sT[qt][j] - mx) : 0.f;
        sum += p[j];
      }
      sum += __shfl_xor(sum, 16);
      sum += __shfl_xor(sum, 32);
      float iv = 1.f / sum;
      union { __hip_bfloat16 h[2]; uint u; } u01, u23;
      u01.h[0] = __float2bfloat16(p[0] * iv); u01.h[1] = __float2bfloat16(p[1] * iv);
      u23.h[0] = __float2bfloat16(p[2] * iv); u23.h[1] = __float2bfloat16(p[3] * iv);
      pk[qt][0] = u01.u; pk[qt][1] = u23.u;
    }

    short8 pfrag[2];
    {
      int g0 = ((hi4 * 2) & 3) * 16 + lo4;
      int g1 = ((hi4 * 2 + 1) & 3) * 16 + lo4;
#pragma unroll
      for (int qt = 0; qt < 2; ++qt) {
        uint w0 = __builtin_amdgcn_ds_bpermute(g0 * 4, pk[qt][0]);
        uint w1 = __builtin_amdgcn_ds_bpermute(g0 * 4, pk[qt][1]);
        uint w2 = __builtin_amdgcn_ds_bpermute(g1 * 4, pk[qt][0]);
        uint w3 = __builtin_amdgcn_ds_bpermute(g1 * 4, pk[qt][1]);
        if (hi4 >= 2) { w0 = 0; w1 = 0; w2 = 0; w3 = 0; }
        union { uint u[4]; short8 s; } asm8;
        asm8.u[0] = w0; asm8.u[1] = w1; asm8.u[2] = w2; asm8.u[3] = w3;
        pfrag[qt] = asm8.s;
      }
    }

    f32x4 oacc[4][2] = {};
    __builtin_amdgcn_s_setprio(1);
#pragma unroll
    for (int dt = 0; dt < 4; ++dt) {
      short8 dtf = *reinterpret_cast<const short8*>(&DlT[dt * 16 + lo4][hi4 * 8]);
#pragma unroll
      for (int qt = 0; qt < 2; ++qt)
        oacc[dt][qt] = __builtin_amdgcn_mfma_f32_16x16x32_bf16(dtf, pfrag[qt], oacc[dt][qt], 0, 0, 0);
    }
    __builtin_amdgcn_s_setprio(0);

#pragma unroll
    for (int qt = 0; qt < 2; ++qt) {
      int q = qt * 16 + lo4;
      if (q < LQ) {
#pragma unroll
        for (int dt = 0; dt < 4; ++dt) {
          f32x4 v = oacc[dt][qt];
          union { __hip_bfloat16 h[4]; uint2 u; } p;
          p.h[0] = __float2bfloat16(v[0]); p.h[1] = __float2bfloat16(v[1]);
          p.h[2] = __float2bfloat16(v[2]); p.h[3] = __float2bfloat16(v[3]);
          *reinterpret_cast<uint2*>(cb + h * (LQ * DH_) + q * DH_ + dt * 16 + hi4 * 4) = p.u;
        }
      }
    }
    asm volatile("s_waitcnt lgkmcnt(0)" ::: "memory");
  }
}

// ---------------------------------------------------------------------------
extern "C" void kernel_launch(void* const* d_in, const int* in_sizes, int n_in,
                              void* d_out, int out_size, void* d_ws, size_t ws_size,
                              hipStream_t stream) {
  const int*   q      = (const int*)d_in[0];
  const int*   dpos   = (const int*)d_in[1];
  const int*   dneg   = (const int*)d_in[2];
  const float* qmask  = (const float*)d_in[3];
  const float* dpmask = (const float*)d_in[4];
  const float* dnmask = (const float*)d_in[5];
  const int*   peflag = (const int*)d_in[6];
  const float* emb    = (const float*)d_in[7];
  const float* Wlin   = (const float*)d_in[8];
  const float* Wout   = (const float*)d_in[9];
  float* out = (float*)d_out;

  (void)hipFuncSetAttribute(reinterpret_cast<const void*>(&gemm_mfma<false>),
                            hipFuncAttributeMaxDynamicSharedMemorySize, 131072);
  (void)hipFuncSetAttribute(reinterpret_cast<const void*>(&gemm_mfma<true>),
                            hipFuncAttributeMaxDynamicSharedMemorySize, 131072);

  char* ws = (char*)d_ws;
  size_t off = 0;
  auto alloc = [&](size_t bytes) -> char* {
    char* p = ws + off; off += (bytes + 255) & ~(size_t)255; return p;
  };
  __hip_bfloat16* Xq   = (__hip_bfloat16*)alloc((size_t)512 * DIM * 2);  // 480 rows + tile pad
  float*          Qsc  = (float*)         alloc((size_t)512 * DIM * 4);  // 480 rows + pad (attn over-reads q=30,31)
  __hip_bfloat16* Wl16 = (__hip_bfloat16*)alloc((size_t)DIM * DIM * 2);
  __hip_bfloat16* Wo16 = (__hip_bfloat16*)alloc((size_t)DIM * DIM * 2);
  float*          PE   = (float*)         alloc((size_t)LD * DIM * 4);   // 3.4 MB

  int SC = NSLOT;
  while (SC > 1) {
    size_t need = off
        + ((size_t)SC * LD + 256) * DIM * 2 * 2                 // X + Y
        + ((size_t)SC * WNUM * LQ + 256) * DIM * 2 + (1u << 20);// ctx
    if (need <= ws_size) break;
    SC >>= 1;
  }
  __hip_bfloat16* X   = (__hip_bfloat16*)alloc(((size_t)SC * LD + 256) * DIM * 2);
  __hip_bfloat16* Y   = (__hip_bfloat16*)alloc(((size_t)SC * LD + 256) * DIM * 2);
  __hip_bfloat16* ctx = (__hip_bfloat16*)alloc(((size_t)SC * WNUM * LQ + 256) * DIM * 2);

  prologue_kernel<<<WCONV_B + PE_B + PQ_B, 256, 0, stream>>>(
      Wlin, Wout, Wl16, Wo16, PE, q, qmask, emb, Xq);

  const int tilesX = DIM / 256;                       // 3
  const int qTiles = tilesX * ((B_ * LQ + 255) / 256);// 6 (Q-problem blocks)

  for (int s0 = 0; s0 < NSLOT; s0 += SC) {
    const int rowsX = SC * LD;           // 35200 at SC=32
    const int rowsC = SC * WNUM * LQ;    // 96000 at SC=32
    prep_d_kernel<<<(rowsX * (DIM / 8) + 255) / 256, 256, 0, stream>>>(
        dpos, dneg, dpmask, dnmask, emb, peflag, PE, X, s0, rowsX);
    {
      int tiles1 = tilesX * ((rowsX + 255) / 256);
      int t2 = (s0 == 0) ? qTiles : 0;
      gemm_mfma<true><<<tiles1 + t2, 512, 131072, stream>>>(
          X, Wl16, Y, rowsX, DIM, DIM, tilesX, tiles1, Xq, Qsc, B_ * LQ);
    }
    attn_kernel<<<SC * WNUM, 64, 0, stream>>>(Qsc, Y, ctx, s0);
    {
      int tiles1 = tilesX * ((rowsC + 255) / 256);
      gemm_mfma<false><<<tiles1, 512, 131072, stream>>>(
          ctx, Wo16, out + (size_t)s0 * WNUM * LQ * DIM, rowsC, DIM, DIM,
          tilesX, tiles1, nullptr, nullptr, 0);
    }
  }
}